// Round 1
// baseline (958.233 us; speedup 1.0000x reference)
//
#include <hip/hip_runtime.h>

// ChannelAttention: b=2, n=4096 (16*16*16), c=32, fp32.
// scores = X X^T (symmetric Gram), softmax over j, out[j,c] = sum_i attn[i,j] x[i,c].
// Pass 1: q[i] = m_i + ln(sum_j exp(s_ij - m_i))  (log-sum-exp per row)
// Pass 2: out[j,c] = sum_i exp(s_ji - q_i) * x[i,c]   (uses s symmetry)
// then out = out*gamma + x.

#define BB 2
#define NN 4096
#define CC 32
#define BN (BB * NN)

// ---------------- Pass 1: per-row log-sum-exp of the Gram matrix ----------------
// One wave (64 lanes) per row i; lanes stride over j. Online softmax per lane,
// butterfly combine across the wave.
__global__ __launch_bounds__(256) void ca_stats_kernel(const float* __restrict__ x,
                                                       float* __restrict__ q) {
    const int wave = threadIdx.x >> 6;
    const int lane = threadIdx.x & 63;
    const int row  = blockIdx.x * 4 + wave;      // 0..BN-1  (b*N + i)
    const int b    = row >> 12;                  // / 4096
    const float* xb = x + (size_t)b * NN * CC;
    const float* xi = x + (size_t)row * CC;

    float4 xr[8];
#pragma unroll
    for (int u = 0; u < 8; ++u) xr[u] = ((const float4*)xi)[u];

    float m = -1e30f, z = 0.f;
    for (int jt = 0; jt < NN / 64; ++jt) {
        const int j = jt * 64 + lane;
        const float4* xj = (const float4*)(xb + (size_t)j * CC);
        float s = 0.f;
#pragma unroll
        for (int u = 0; u < 8; ++u) {
            float4 v = xj[u];
            s += xr[u].x * v.x + xr[u].y * v.y + xr[u].z * v.z + xr[u].w * v.w;
        }
        float nm = fmaxf(m, s);
        z = z * __expf(m - nm) + __expf(s - nm);
        m = nm;
    }
    // butterfly combine (m, z) across 64 lanes
#pragma unroll
    for (int off = 32; off >= 1; off >>= 1) {
        float om = __shfl_xor(m, off, 64);
        float oz = __shfl_xor(z, off, 64);
        float nm = fmaxf(m, om);
        z = z * __expf(m - nm) + oz * __expf(om - nm);
        m = nm;
    }
    if (lane == 0) q[row] = m + __logf(z);
}

// ---------------- Pass 2: weighted accumulation ----------------
// One wave per OUTPUT row j; lanes stride over i. Each lane accumulates a full
// 32-channel partial; butterfly-sum across lanes at the end.
__global__ __launch_bounds__(256) void ca_out_kernel(const float* __restrict__ x,
                                                     const float* __restrict__ q,
                                                     const float* __restrict__ gamma,
                                                     float* __restrict__ out) {
    const int wave = threadIdx.x >> 6;
    const int lane = threadIdx.x & 63;
    const int row  = blockIdx.x * 4 + wave;      // output row (b*N + j)
    const int b    = row >> 12;
    const float* xb = x + (size_t)b * NN * CC;
    const float* qb = q + b * NN;
    const float* xjp = x + (size_t)row * CC;

    float4 xj[8];
#pragma unroll
    for (int u = 0; u < 8; ++u) xj[u] = ((const float4*)xjp)[u];

    float acc[32];
#pragma unroll
    for (int c = 0; c < 32; ++c) acc[c] = 0.f;

    for (int it = 0; it < NN / 64; ++it) {
        const int i = it * 64 + lane;
        const float4* xi4 = (const float4*)(xb + (size_t)i * CC);
        float4 xi[8];
#pragma unroll
        for (int u = 0; u < 8; ++u) xi[u] = xi4[u];
        float s = 0.f;
#pragma unroll
        for (int u = 0; u < 8; ++u)
            s += xj[u].x * xi[u].x + xj[u].y * xi[u].y + xj[u].z * xi[u].z + xj[u].w * xi[u].w;
        const float w = __expf(s - qb[i]);   // s[j,i] == s[i,j]; normalizer is per-i
#pragma unroll
        for (int u = 0; u < 8; ++u) {
            acc[4 * u + 0] += w * xi[u].x;
            acc[4 * u + 1] += w * xi[u].y;
            acc[4 * u + 2] += w * xi[u].z;
            acc[4 * u + 3] += w * xi[u].w;
        }
    }

    // butterfly-sum all 32 accumulators across the 64 lanes
#pragma unroll
    for (int off = 32; off >= 1; off >>= 1) {
#pragma unroll
        for (int c = 0; c < 32; ++c)
            acc[c] += __shfl_xor(acc[c], off, 64);
    }

    if (lane == 0) {
        const float g = gamma[0];
        float4* o4 = (float4*)(out + (size_t)row * CC);
        const float4* r4 = (const float4*)xjp;
#pragma unroll
        for (int u = 0; u < 8; ++u) {
            float4 r = r4[u];
            float4 a;
            a.x = acc[4 * u + 0] * g + r.x;
            a.y = acc[4 * u + 1] * g + r.y;
            a.z = acc[4 * u + 2] * g + r.z;
            a.w = acc[4 * u + 3] * g + r.w;
            o4[u] = a;
        }
    }
}

extern "C" void kernel_launch(void* const* d_in, const int* in_sizes, int n_in,
                              void* d_out, int out_size, void* d_ws, size_t ws_size,
                              hipStream_t stream) {
    const float* x     = (const float*)d_in[0];
    const float* gamma = (const float*)d_in[1];
    float* out = (float*)d_out;
    float* q   = (float*)d_ws;                  // BN floats = 32 KB

    ca_stats_kernel<<<dim3(BN / 4), dim3(256), 0, stream>>>(x, q);
    ca_out_kernel<<<dim3(BN / 4), dim3(256), 0, stream>>>(x, q, gamma, out);
}

// Round 2
// 99.394 us; speedup vs baseline: 9.6408x; 9.6408x over previous
//
#include <hip/hip_runtime.h>

// ChannelAttention b=2, n=4096, c=32 fp32.
// S = X X^T (Gram), softmax over j per row i, out[j,c] = sum_i attn[i,j] x[i,c]; out*g + x.
//
// MFMA plan (16x16x32 f16, K = c = 32):
//  k0: convert x -> Xf16 [b][n][c] and XT f16 [b][c][n]  (ws)
//  k1: Z_i = sum_j exp(s_ij - 48)  via S-MFMA tiles; store c2[i] = -log2(Z_i) - 48*log2e
//  k2: out-tile per 16 j's: loop i: S-MFMA -> attn=exp2(s*log2e + c2[i]) (fp16)
//      -> LDS round-trip to A-operand layout -> PV-MFMA with XT; block-reduce 4 waves.
//
// Layout facts used (HW-verified per guide):
//  A-frag: A[m=lane&15][k=quad*8+t] (t=0..7, contiguous 16B)
//  B-frag: B^T rows, same pattern (gemm_bt)
//  C/D:    col = lane&15, row = quad*4 + reg

typedef _Float16 half8 __attribute__((ext_vector_type(8)));
typedef _Float16 half4v __attribute__((ext_vector_type(4)));
typedef float float4v __attribute__((ext_vector_type(4)));

#define NN 4096
#define CC 32
#define L2E 1.44269504f
#define SHIFT 48.0f

// ---------------- k0: fp32 -> fp16 row-major + fp16 transposed ----------------
__global__ __launch_bounds__(256) void k_convert(const float* __restrict__ x,
                                                 _Float16* __restrict__ xf,
                                                 _Float16* __restrict__ xt) {
    const int t = blockIdx.x * 256 + threadIdx.x;   // 65536 threads
    const int n  = t & 4095;
    const int cg = (t >> 12) & 7;
    const int b  = t >> 15;
    const int row = (b << 12) | n;
    const float4* src = (const float4*)(x + (size_t)row * CC + cg * 4);
    float4 v = *src;
    _Float16 h0 = (_Float16)v.x, h1 = (_Float16)v.y, h2 = (_Float16)v.z, h3 = (_Float16)v.w;
    *(half4v*)(xf + (size_t)row * CC + cg * 4) = (half4v){h0, h1, h2, h3};
    _Float16* xtb = xt + (size_t)b * CC * NN;
    xtb[(cg * 4 + 0) * NN + n] = h0;
    xtb[(cg * 4 + 1) * NN + n] = h1;
    xtb[(cg * 4 + 2) * NN + n] = h2;
    xtb[(cg * 4 + 3) * NN + n] = h3;
}

// ---------------- k1: per-row shifted sum-of-exp -> c2[i] ----------------
// Block = one 16-row i-tile; 4 waves split the j range (1024 j's each).
__global__ __launch_bounds__(256) void k_pass1(const _Float16* __restrict__ xf,
                                               float* __restrict__ c2out) {
    const int tid = threadIdx.x;
    const int wave = tid >> 6, lane = tid & 63;
    const int quad = lane >> 4, l15 = lane & 15;
    const int b = blockIdx.x >> 8;
    const int i0 = (blockIdx.x & 255) * 16;
    const _Float16* xb = xf + (size_t)b * NN * CC;

    const half8 afrag = *(const half8*)(xb + (size_t)(i0 + l15) * CC + quad * 8);
    const float4v zf = {0.f, 0.f, 0.f, 0.f};
    float z[4] = {0.f, 0.f, 0.f, 0.f};
    const float c2c = -SHIFT * L2E;

    for (int jt = wave * 64; jt < wave * 64 + 64; jt += 2) {
        const int j0 = jt * 16;
        half8 b0 = *(const half8*)(xb + (size_t)(j0 + l15) * CC + quad * 8);
        half8 b1 = *(const half8*)(xb + (size_t)(j0 + 16 + l15) * CC + quad * 8);
        float4v s0 = __builtin_amdgcn_mfma_f32_16x16x32_f16(afrag, b0, zf, 0, 0, 0);
        float4v s1 = __builtin_amdgcn_mfma_f32_16x16x32_f16(afrag, b1, zf, 0, 0, 0);
#pragma unroll
        for (int r = 0; r < 4; ++r) {
            z[r] += __builtin_amdgcn_exp2f(fmaf(s0[r], L2E, c2c));
            z[r] += __builtin_amdgcn_exp2f(fmaf(s1[r], L2E, c2c));
        }
    }
    // combine over the 16 j-lanes within each quad group
#pragma unroll
    for (int off = 1; off <= 8; off <<= 1) {
#pragma unroll
        for (int r = 0; r < 4; ++r) z[r] += __shfl_xor(z[r], off, 64);
    }
    __shared__ float zw[4][16];
    if (l15 == 0) {
#pragma unroll
        for (int r = 0; r < 4; ++r) zw[wave][quad * 4 + r] = z[r];
    }
    __syncthreads();
    if (tid < 16) {
        float zs = zw[0][tid] + zw[1][tid] + zw[2][tid] + zw[3][tid];
        // c2[i] = log2(1/Z) - 48*log2e
        c2out[b * NN + i0 + tid] = -(__builtin_amdgcn_logf(zs) + SHIFT * L2E);
    }
}

// ---------------- k2: output pass ----------------
// Block = one 16-row j-tile; 4 waves split the i range; LDS reduce at end.
__global__ __launch_bounds__(256) void k_pass2(const _Float16* __restrict__ xf,
                                               const _Float16* __restrict__ xt,
                                               const float* __restrict__ c2,
                                               const float* __restrict__ x,
                                               const float* __restrict__ gamma,
                                               float* __restrict__ out) {
    const int tid = threadIdx.x;
    const int wave = tid >> 6, lane = tid & 63;
    const int quad = lane >> 4, l15 = lane & 15;
    const int b = blockIdx.x >> 8;
    const int j0 = (blockIdx.x & 255) * 16;
    const _Float16* xb  = xf + (size_t)b * NN * CC;
    const _Float16* xtb = xt + (size_t)b * CC * NN;
    const float* c2b = c2 + b * NN;

    __shared__ _Float16 pt[4][16][40];   // per-wave P^T tile [j][i], stride 40 (16B-aligned rows)
    __shared__ float red[4][16][32];

    const half8 bjfrag = *(const half8*)(xb + (size_t)(j0 + l15) * CC + quad * 8);
    const float4v zf = {0.f, 0.f, 0.f, 0.f};
    float4v acc0 = zf, acc1 = zf;
    _Float16* ptw = &pt[wave][0][0];

    for (int ii = wave * 1024; ii < wave * 1024 + 1024; ii += 32) {
        half8 a0 = *(const half8*)(xb + (size_t)(ii + l15) * CC + quad * 8);
        half8 a1 = *(const half8*)(xb + (size_t)(ii + 16 + l15) * CC + quad * 8);
        float4v s0 = __builtin_amdgcn_mfma_f32_16x16x32_f16(a0, bjfrag, zf, 0, 0, 0);
        float4v s1 = __builtin_amdgcn_mfma_f32_16x16x32_f16(a1, bjfrag, zf, 0, 0, 0);
        // attn = exp2(s * log2e + c2[i]);  lane holds j=l15, i = ii + (0|16) + quad*4 + r
        const float* c2p = c2b + ii + quad * 4;
        half4v p0, p1;
#pragma unroll
        for (int r = 0; r < 4; ++r) {
            p0[r] = (_Float16)__builtin_amdgcn_exp2f(fmaf(s0[r], L2E, c2p[r]));
            p1[r] = (_Float16)__builtin_amdgcn_exp2f(fmaf(s1[r], L2E, c2p[16 + r]));
        }
        // LDS round-trip: C-layout -> A-operand layout (within-wave only)
        *(half4v*)(ptw + l15 * 40 + quad * 4)      = p0;
        *(half4v*)(ptw + l15 * 40 + 16 + quad * 4) = p1;
        asm volatile("s_waitcnt lgkmcnt(0)" ::: "memory");
        half8 a2  = *(const half8*)(ptw + l15 * 40 + quad * 8);           // P^T[j=l15][i]
        half8 b20 = *(const half8*)(xtb + (size_t)l15 * NN + ii + quad * 8);        // c 0..15
        half8 b21 = *(const half8*)(xtb + (size_t)(l15 + 16) * NN + ii + quad * 8); // c 16..31
        acc0 = __builtin_amdgcn_mfma_f32_16x16x32_f16(a2, b20, acc0, 0, 0, 0);
        acc1 = __builtin_amdgcn_mfma_f32_16x16x32_f16(a2, b21, acc1, 0, 0, 0);
        asm volatile("s_waitcnt lgkmcnt(0)" ::: "memory");  // protect pt WAR before next iter
    }

    // block reduction across the 4 waves
#pragma unroll
    for (int r = 0; r < 4; ++r) {
        red[wave][quad * 4 + r][l15]      = acc0[r];
        red[wave][quad * 4 + r][l15 + 16] = acc1[r];
    }
    __syncthreads();
    {
        const int idx = tid * 2;
        const int jj = idx >> 5, c = idx & 31;
        float s0 = red[0][jj][c] + red[1][jj][c] + red[2][jj][c] + red[3][jj][c];
        float s1 = red[0][jj][c + 1] + red[1][jj][c + 1] + red[2][jj][c + 1] + red[3][jj][c + 1];
        const float g = gamma[0];
        const int row = b * NN + j0 + jj;
        out[(size_t)row * CC + c]     = fmaf(g, s0, x[(size_t)row * CC + c]);
        out[(size_t)row * CC + c + 1] = fmaf(g, s1, x[(size_t)row * CC + c + 1]);
    }
}

extern "C" void kernel_launch(void* const* d_in, const int* in_sizes, int n_in,
                              void* d_out, int out_size, void* d_ws, size_t ws_size,
                              hipStream_t stream) {
    const float* x     = (const float*)d_in[0];
    const float* gamma = (const float*)d_in[1];
    float* out = (float*)d_out;

    // ws layout: Xf16 (512 KB) | XT f16 (512 KB) | c2 fp32 (32 KB)
    _Float16* xf = (_Float16*)d_ws;
    _Float16* xt = xf + (size_t)2 * NN * CC;
    float*    c2 = (float*)(xt + (size_t)2 * CC * NN);

    k_convert<<<dim3(256), dim3(256), 0, stream>>>(x, xf, xt);
    k_pass1 <<<dim3(512), dim3(256), 0, stream>>>(xf, c2);
    k_pass2 <<<dim3(512), dim3(256), 0, stream>>>(xf, xt, c2, x, gamma, out);
}

// Round 3
// 94.700 us; speedup vs baseline: 10.1186x; 1.0496x over previous
//
#include <hip/hip_runtime.h>

// ChannelAttention b=2, n=4096, c=32 fp32.
// S = X X^T (Gram), softmax over j per row i, out[j,c] = sum_i attn[i,j] x[i,c]; out*g + x.
//
// MFMA plan (16x16x32 f16, K = c = 32):
//  k0: convert x -> Xf16 [b][n][c] and XT f16 [b][c][n]  (ws)
//  k1: Z_i = sum_j exp(s_ij - 48); store c2[i] = -log2(Z_i) - 48*log2e
//  k2: per 16-j tile: loop i: S-MFMA -> attn=exp2(s*log2e + c2[i]) (fp16)
//      -> per-wave double-buffered LDS round-trip (C-layout -> A-layout) -> PV-MFMA.
//
// R2 -> R3: removed asm waitcnt/memory-clobber barriers (they blocked load
// pipelining), double-buffered the P tile, manual prefetch of next-iter
// global loads, 8 waves/block (16 waves/CU) in both passes, 4 tiles/iter in k1.

typedef _Float16 half8 __attribute__((ext_vector_type(8)));
typedef _Float16 half4v __attribute__((ext_vector_type(4)));
typedef float float4v __attribute__((ext_vector_type(4)));

#define NN 4096
#define CC 32
#define L2E 1.44269504f
#define SHIFT 48.0f

// ---------------- k0: fp32 -> fp16 row-major + fp16 transposed ----------------
__global__ __launch_bounds__(256) void k_convert(const float* __restrict__ x,
                                                 _Float16* __restrict__ xf,
                                                 _Float16* __restrict__ xt) {
    const int t = blockIdx.x * 256 + threadIdx.x;   // 65536 threads
    const int n  = t & 4095;
    const int cg = (t >> 12) & 7;
    const int b  = t >> 15;
    const int row = (b << 12) | n;
    const float4* src = (const float4*)(x + (size_t)row * CC + cg * 4);
    float4 v = *src;
    _Float16 h0 = (_Float16)v.x, h1 = (_Float16)v.y, h2 = (_Float16)v.z, h3 = (_Float16)v.w;
    *(half4v*)(xf + (size_t)row * CC + cg * 4) = (half4v){h0, h1, h2, h3};
    _Float16* xtb = xt + (size_t)b * CC * NN;
    xtb[(cg * 4 + 0) * NN + n] = h0;   // consecutive lanes -> consecutive n: coalesced
    xtb[(cg * 4 + 1) * NN + n] = h1;
    xtb[(cg * 4 + 2) * NN + n] = h2;
    xtb[(cg * 4 + 3) * NN + n] = h3;
}

// ---------------- k1: per-row shifted sum-of-exp -> c2[i] ----------------
// Block = 512 threads (8 waves), one 16-row i-tile; each wave covers 512 j's,
// 4 independent B-tiles per iteration for MLP.
__global__ __launch_bounds__(512) void k_pass1(const _Float16* __restrict__ xf,
                                               float* __restrict__ c2out) {
    const int tid = threadIdx.x;
    const int wave = tid >> 6, lane = tid & 63;
    const int quad = lane >> 4, l15 = lane & 15;
    const int b = blockIdx.x >> 8;
    const int i0 = (blockIdx.x & 255) * 16;
    const _Float16* xb = xf + (size_t)b * NN * CC;

    const half8 afrag = *(const half8*)(xb + (size_t)(i0 + l15) * CC + quad * 8);
    const float4v zf = {0.f, 0.f, 0.f, 0.f};
    float z[4] = {0.f, 0.f, 0.f, 0.f};
    const float c2c = -SHIFT * L2E;

    const int jbase = wave * 512;
    for (int jt = 0; jt < 8; ++jt) {           // 8 iters x 4 tiles x 16 j = 512 j
        const int j0 = jbase + jt * 64;
        half8 b0 = *(const half8*)(xb + (size_t)(j0 + l15) * CC + quad * 8);
        half8 b1 = *(const half8*)(xb + (size_t)(j0 + 16 + l15) * CC + quad * 8);
        half8 b2 = *(const half8*)(xb + (size_t)(j0 + 32 + l15) * CC + quad * 8);
        half8 b3 = *(const half8*)(xb + (size_t)(j0 + 48 + l15) * CC + quad * 8);
        float4v s0 = __builtin_amdgcn_mfma_f32_16x16x32_f16(afrag, b0, zf, 0, 0, 0);
        float4v s1 = __builtin_amdgcn_mfma_f32_16x16x32_f16(afrag, b1, zf, 0, 0, 0);
        float4v s2 = __builtin_amdgcn_mfma_f32_16x16x32_f16(afrag, b2, zf, 0, 0, 0);
        float4v s3 = __builtin_amdgcn_mfma_f32_16x16x32_f16(afrag, b3, zf, 0, 0, 0);
#pragma unroll
        for (int r = 0; r < 4; ++r) {
            z[r] += __builtin_amdgcn_exp2f(fmaf(s0[r], L2E, c2c));
            z[r] += __builtin_amdgcn_exp2f(fmaf(s1[r], L2E, c2c));
            z[r] += __builtin_amdgcn_exp2f(fmaf(s2[r], L2E, c2c));
            z[r] += __builtin_amdgcn_exp2f(fmaf(s3[r], L2E, c2c));
        }
    }
    // combine over the 16 j-lanes within each quad group
#pragma unroll
    for (int off = 1; off <= 8; off <<= 1) {
#pragma unroll
        for (int r = 0; r < 4; ++r) z[r] += __shfl_xor(z[r], off, 64);
    }
    __shared__ float zw[8][16];
    if (l15 == 0) {
#pragma unroll
        for (int r = 0; r < 4; ++r) zw[wave][quad * 4 + r] = z[r];
    }
    __syncthreads();
    if (tid < 16) {
        float zs = 0.f;
#pragma unroll
        for (int w = 0; w < 8; ++w) zs += zw[w][tid];
        c2out[b * NN + i0 + tid] = -(__builtin_amdgcn_logf(zs) + SHIFT * L2E);
    }
}

// ---------------- k2: output pass ----------------
// Block = 512 threads (8 waves), one 16-j tile; wave w covers i in [w*512,(w+1)*512),
// 32 i per iteration (16 iters). Double-buffered per-wave P^T LDS tile; manual
// prefetch of next-iter A-tiles / XT-frags / c2. No asm barriers: compiler
// tracks the within-wave LDS RAW via lgkmcnt.
__global__ __launch_bounds__(512) void k_pass2(const _Float16* __restrict__ xf,
                                               const _Float16* __restrict__ xt,
                                               const float* __restrict__ c2,
                                               const float* __restrict__ x,
                                               const float* __restrict__ gamma,
                                               float* __restrict__ out) {
    const int tid = threadIdx.x;
    const int wave = tid >> 6, lane = tid & 63;
    const int quad = lane >> 4, l15 = lane & 15;
    const int b = blockIdx.x >> 8;
    const int j0 = (blockIdx.x & 255) * 16;
    const _Float16* xb  = xf + (size_t)b * NN * CC;
    const _Float16* xtb = xt + (size_t)b * CC * NN;
    const float* c2b = c2 + b * NN;

    __shared__ _Float16 pt[8][2][16 * 40];   // wave x parity x (16 rows, stride 40)
    __shared__ float red[8][16][32];

    const half8 bjfrag = *(const half8*)(xb + (size_t)(j0 + l15) * CC + quad * 8);
    const float4v zf = {0.f, 0.f, 0.f, 0.f};
    float4v acc0 = zf, acc1 = zf;

    const int ibase = wave * 512;
    // prologue loads (iteration 0)
    half8 a0  = *(const half8*)(xb + (size_t)(ibase + l15) * CC + quad * 8);
    half8 a1  = *(const half8*)(xb + (size_t)(ibase + 16 + l15) * CC + quad * 8);
    half8 xb0 = *(const half8*)(xtb + (size_t)l15 * NN + ibase + quad * 8);
    half8 xb1 = *(const half8*)(xtb + (size_t)(l15 + 16) * NN + ibase + quad * 8);
    float4v c20 = *(const float4v*)(c2b + ibase + quad * 4);
    float4v c21 = *(const float4v*)(c2b + ibase + 16 + quad * 4);

    for (int it = 0; it < 16; ++it) {
        // prefetch next iteration (wraps to iter 0's addresses on the last — harmless)
        const int inx = ibase + ((it + 1) & 15) * 32;
        half8 na0  = *(const half8*)(xb + (size_t)(inx + l15) * CC + quad * 8);
        half8 na1  = *(const half8*)(xb + (size_t)(inx + 16 + l15) * CC + quad * 8);
        half8 nxb0 = *(const half8*)(xtb + (size_t)l15 * NN + inx + quad * 8);
        half8 nxb1 = *(const half8*)(xtb + (size_t)(l15 + 16) * NN + inx + quad * 8);
        float4v nc20 = *(const float4v*)(c2b + inx + quad * 4);
        float4v nc21 = *(const float4v*)(c2b + inx + 16 + quad * 4);

        float4v s0 = __builtin_amdgcn_mfma_f32_16x16x32_f16(a0, bjfrag, zf, 0, 0, 0);
        float4v s1 = __builtin_amdgcn_mfma_f32_16x16x32_f16(a1, bjfrag, zf, 0, 0, 0);
        half4v p0, p1;
#pragma unroll
        for (int r = 0; r < 4; ++r) {
            p0[r] = (_Float16)__builtin_amdgcn_exp2f(fmaf(s0[r], L2E, c20[r]));
            p1[r] = (_Float16)__builtin_amdgcn_exp2f(fmaf(s1[r], L2E, c21[r]));
        }
        // LDS round-trip: C-layout -> A-operand layout (within-wave, double-buffered)
        _Float16* ptw = &pt[wave][it & 1][0];
        *(half4v*)(ptw + l15 * 40 + quad * 4)      = p0;
        *(half4v*)(ptw + l15 * 40 + 16 + quad * 4) = p1;
        half8 a2 = *(const half8*)(ptw + l15 * 40 + quad * 8);   // P^T[j=l15][i]
        acc0 = __builtin_amdgcn_mfma_f32_16x16x32_f16(a2, xb0, acc0, 0, 0, 0);
        acc1 = __builtin_amdgcn_mfma_f32_16x16x32_f16(a2, xb1, acc1, 0, 0, 0);

        a0 = na0; a1 = na1; xb0 = nxb0; xb1 = nxb1; c20 = nc20; c21 = nc21;
    }

    // block reduction across the 8 waves
#pragma unroll
    for (int r = 0; r < 4; ++r) {
        red[wave][quad * 4 + r][l15]      = acc0[r];
        red[wave][quad * 4 + r][l15 + 16] = acc1[r];
    }
    __syncthreads();
    {
        const int jj = tid >> 5, c = tid & 31;   // 512 threads = 16 j x 32 c
        float s = 0.f;
#pragma unroll
        for (int w = 0; w < 8; ++w) s += red[w][jj][c];
        const float g = gamma[0];
        const size_t o = (size_t)(b * NN + j0 + jj) * CC + c;
        out[o] = fmaf(g, s, x[o]);
    }
}

extern "C" void kernel_launch(void* const* d_in, const int* in_sizes, int n_in,
                              void* d_out, int out_size, void* d_ws, size_t ws_size,
                              hipStream_t stream) {
    const float* x     = (const float*)d_in[0];
    const float* gamma = (const float*)d_in[1];
    float* out = (float*)d_out;

    // ws layout: Xf16 (512 KB) | XT f16 (512 KB) | c2 fp32 (32 KB)
    _Float16* xf = (_Float16*)d_ws;
    _Float16* xt = xf + (size_t)2 * NN * CC;
    float*    c2 = (float*)(xt + (size_t)2 * CC * NN);

    k_convert<<<dim3(256), dim3(256), 0, stream>>>(x, xf, xt);
    k_pass1 <<<dim3(512), dim3(512), 0, stream>>>(xf, c2);
    k_pass2 <<<dim3(512), dim3(512), 0, stream>>>(xf, xt, c2, x, gamma, out);
}